// Round 10
// baseline (4166.974 us; speedup 1.0000x reference)
//
#include <hip/hip_runtime.h>
#include <hip/hip_bf16.h>

// B=2048, T=100, I=1, H=512. Output: h at t=84..99 -> (2048,16,512) fp32.
// Step: K_A darnn_gemm2 (512 WGs, uniform 64x160 tiles over N=2560:
//         [s | gates] = h @ Wall^T, Wall = [Wcs(512) ; Wcg(2048)] rows) ;
//       K_B darnn_attn_lstm (2048 WGs, 1 row/WG: attn -> wm, LSTM update).
// ws layout (bytes), total 29884416:
//   Wcs  bf16 [512][512]   @ 0         (= W2_w)          } Wall[2560][512]
//   Wcg  bf16 [2048][512]  @ 524288    (row 4j+g = Whh[g*512+j]) } contiguous
//   hbf  bf16 [2048][512]  @ 2621440
//   cst  f32  [2048][512]  @ 4718592
//   sbuf f32  [2048][512]  @ 8912896
//   gpre f32  [2048][2048] @ 13107200  (col 4j+g, interleaved gates)

typedef __attribute__((ext_vector_type(8))) short s16x8;
typedef __attribute__((ext_vector_type(4))) float f32x4;

#define LOG2E 1.4426950408889634f

__device__ __forceinline__ float fexp2(float x) {
  float r; asm("v_exp_f32 %0, %1\n\ts_nop 1" : "=v"(r) : "v"(x)); return r;
}
__device__ __forceinline__ float frcp(float x) {
  float r; asm("v_rcp_f32 %0, %1\n\ts_nop 1" : "=v"(r) : "v"(x)); return r;
}
__device__ __forceinline__ float ftanh(float y) {   // tanh(y) = 1 - 2/(1+e^{2y})
  return 1.0f - 2.0f * frcp(1.0f + fexp2(y * (2.0f * LOG2E)));
}
__device__ __forceinline__ float fsig(float y) {
  return frcp(1.0f + fexp2(-y * LOG2E));
}

__device__ __forceinline__ void gl_lds16(const void* g, void* l) {
  __builtin_amdgcn_global_load_lds(
      (const __attribute__((address_space(1))) void*)g,
      (__attribute__((address_space(3))) void*)l, 16, 0, 0);
}

// ---------------- prologue: zero h,c ; build bf16 weights ------------------
__global__ __launch_bounds__(256) void darnn_prologue(
    const float* __restrict__ W2w, const float* __restrict__ Whh,
    __hip_bfloat16* __restrict__ Wcs, __hip_bfloat16* __restrict__ Wcg,
    __hip_bfloat16* __restrict__ hbf, float* __restrict__ cst)
{
  const int gtid = blockIdx.x * 256 + threadIdx.x;        // 0..131071
  s16x8 z8 = {0, 0, 0, 0, 0, 0, 0, 0};
  ((s16x8*)hbf)[gtid] = z8;                               // 2048*512 bf16
  f32x4 zf = {0.f, 0.f, 0.f, 0.f};
  ((f32x4*)cst)[gtid] = zf;                               // 2048*512 f32
  ((f32x4*)cst)[gtid + 131072] = zf;
  // Wcs = bf16(W2w), same layout (512*512 = 2 per thread)
  Wcs[2 * gtid]     = __float2bfloat16(W2w[2 * gtid]);
  Wcs[2 * gtid + 1] = __float2bfloat16(W2w[2 * gtid + 1]);
  // Wcg: row r=4j+g <- Whh row g*512+j   (2048*512 = 8 per thread, same row)
  {
    int base = gtid * 8;
    int r = base >> 9, kk = base & 511;
    int j = r >> 2, g = r & 3;
    const float* src = Whh + ((size_t)((g << 9) + j) << 9) + kk;
#pragma unroll
    for (int e = 0; e < 8; ++e) Wcg[base + e] = __float2bfloat16(src[e]);
  }
}

// -------- K_A: uniform combined GEMM [s | gates] = h @ Wall^T --------------
// 512 WGs x 256 thr, tile 64x160, BK=64, 3 blocks/CU, XCD-swizzled grid.
// Frag layouts m89-verified: C/D col=lane&15, row=(lane>>4)*4+e;
// A/B frag row/col=lane&15, k=(lane>>4)*8.
__global__ __launch_bounds__(256, 3) void darnn_gemm2(
    const __hip_bfloat16* __restrict__ hbf, const __hip_bfloat16* __restrict__ Wall,
    float* __restrict__ sbuf, float* __restrict__ gpre)
{
  const int tid = threadIdx.x;
  const int lane = tid & 63, wv = tid >> 6;

  // XCD swizzle (512 % 8 == 0, bijective): XCD k owns 2 N-tiles x all M-tiles
  // so its 320KB B-panel stays L2-resident.
  const int wg0 = blockIdx.x;
  const int xcd = wg0 & 7, idx = wg0 >> 3;         // idx 0..63
  const int nt = (xcd << 1) + (idx & 1);           // 0..15
  const int mt = idx >> 1;                         // 0..31

  __shared__ __align__(16) short ldsA[64 * 64];    // 8 KB  (h tile)
  __shared__ __align__(16) short ldsB[160 * 64];   // 20 KB (Wall tile)

  const int m0 = mt << 6, n0 = nt * 160;
  const int wm = wv >> 1, wn = wv & 1;             // wave = 32x80 sub-tile
  const int lr = lane & 15, lq = lane >> 4;
  const int r8 = lane >> 3, kk8 = (lane & 7) << 3;

  f32x4 acc[2][5];
#pragma unroll
  for (int i = 0; i < 2; ++i)
#pragma unroll
    for (int j = 0; j < 5; ++j) acc[i][j] = {0.f, 0.f, 0.f, 0.f};

  for (int k0 = 0; k0 < 512; k0 += 64) {
    // stage 28 x 1KB chunks (8 A + 20 B), 7 per wave, each lane covers 16B
#pragma unroll
    for (int cc = 0; cc < 7; ++cc) {
      int c = wv * 7 + cc;
      if (c < 8) {
        gl_lds16(hbf + ((size_t)(m0 + (c << 3) + r8) << 9) + (k0 + kk8),
                 (void*)(ldsA + (c << 9)));
      } else {
        int cb = c - 8;
        gl_lds16(Wall + ((size_t)(n0 + (cb << 3) + r8) << 9) + (k0 + kk8),
                 (void*)(ldsB + (cb << 9)));
      }
    }
    __syncthreads();
#pragma unroll
    for (int kh = 0; kh < 2; ++kh) {
      s16x8 af[2], bfr[5];
      int kk = (kh << 5) + (lq << 3);
#pragma unroll
      for (int i = 0; i < 2; ++i)
        af[i] = *(const s16x8*)(ldsA + ((wm << 5) + (i << 4) + lr) * 64 + kk);
#pragma unroll
      for (int j = 0; j < 5; ++j)
        bfr[j] = *(const s16x8*)(ldsB + (wn * 80 + (j << 4) + lr) * 64 + kk);
#pragma unroll
      for (int i = 0; i < 2; ++i)
#pragma unroll
        for (int j = 0; j < 5; ++j)
          acc[i][j] = __builtin_amdgcn_mfma_f32_16x16x32_bf16(
              af[i], bfr[j], acc[i][j], 0, 0, 0);
    }
    __syncthreads();
  }
  // epilogue: cols [0,512) -> sbuf ; cols [512,2560) -> gpre (gate-interleaved)
#pragma unroll
  for (int i = 0; i < 2; ++i)
#pragma unroll
    for (int j = 0; j < 5; ++j) {
      int row0 = m0 + (wm << 5) + (i << 4) + (lq << 2);
      int col = n0 + wn * 80 + (j << 4) + lr;
#pragma unroll
      for (int e = 0; e < 4; ++e) {
        float v = acc[i][j][e];
        if (col < 512) sbuf[((size_t)(row0 + e) << 9) + col] = v;
        else gpre[((size_t)(row0 + e) << 11) + (col - 512)] = v;
      }
    }
}

// ------- K_B: attention + LSTM, one batch-row per WG (2048 WGs) ------------
// Gate/const loads issued early (hide HBM latency under the tanh loop).
__global__ __launch_bounds__(256, 4) void darnn_attn_lstm(
    const float* __restrict__ x, const float* __restrict__ W1w,
    const float* __restrict__ W1b, const float* __restrict__ W2b,
    const float* __restrict__ vw, const float* __restrict__ sbuf,
    const float* __restrict__ gpre, const float* __restrict__ Wih,
    const float* __restrict__ bih, const float* __restrict__ bhh,
    float* __restrict__ cst, __hip_bfloat16* __restrict__ hbf,
    float* __restrict__ out, int t)
{
  const int b = blockIdx.x, tid = threadIdx.x;
  const int lane = tid & 63, wv = tid >> 6;

  __shared__ float l_logit[100];
  __shared__ float xs[104];
  __shared__ float l_wm;

  // ---- early loads for the LSTM epilogue (j = tid and tid+256) ----
  const f32x4 g4a = *(const f32x4*)(gpre + ((size_t)b << 11) + (tid << 2));
  const f32x4 g4b = *(const f32x4*)(gpre + ((size_t)b << 11) + (tid << 2) + 1024);
  float wih_[2][4], bia_[2][4], cold[2];
#pragma unroll
  for (int p = 0; p < 2; ++p) {
    int j = tid + (p << 8);
#pragma unroll
    for (int g = 0; g < 4; ++g) {
      wih_[p][g] = Wih[(g << 9) + j];
      bia_[p][g] = bih[(g << 9) + j] + bhh[(g << 9) + j];
    }
    cold[p] = cst[((size_t)b << 9) + j];
  }

  if (tid < 100) xs[tid] = x[b * 100 + tid];

  // per-lane slice of 8 h-indices
  float cw1[8], base[8], vvv[8];
  {
    int h0 = lane * 8;
    const f32x4 s0 = *(const f32x4*)(sbuf + ((size_t)b << 9) + h0);
    const f32x4 s1 = *(const f32x4*)(sbuf + ((size_t)b << 9) + h0 + 4);
#pragma unroll
    for (int e = 0; e < 8; ++e) {
      cw1[e] = W1w[h0 + e];
      vvv[e] = vw[h0 + e];
      float s = (e < 4) ? s0[e] : s1[e - 4];
      base[e] = s + W1b[h0 + e] + W2b[h0 + e];
    }
  }
  __syncthreads();

  // logits over suffix t..99 (wave w: tp = t+w, t+w+4, ...)
  for (int tp = t + wv; tp < 100; tp += 4) {
    float xv = xs[tp];
    float a = 0.f;
#pragma unroll
    for (int e = 0; e < 8; ++e) {
      float arg = fmaf(xv, cw1[e], base[e]);
      a = fmaf(vvv[e], ftanh(arg), a);
    }
    a += __shfl_xor(a, 32); a += __shfl_xor(a, 16); a += __shfl_xor(a, 8);
    a += __shfl_xor(a, 4);  a += __shfl_xor(a, 2);  a += __shfl_xor(a, 1);
    if (lane == 0) l_logit[tp] = a;
  }
  __syncthreads();

  // softmax over [t,100) + weighted mean of x (wave 0)
  if (wv == 0) {
    int t0 = t + lane, t1 = t + 64 + lane;
    float v0 = (t0 < 100) ? l_logit[t0] : -1e30f;
    float v1 = (t1 < 100) ? l_logit[t1] : -1e30f;
    float mx = fmaxf(v0, v1);
    mx = fmaxf(mx, __shfl_xor(mx, 32)); mx = fmaxf(mx, __shfl_xor(mx, 16));
    mx = fmaxf(mx, __shfl_xor(mx, 8));  mx = fmaxf(mx, __shfl_xor(mx, 4));
    mx = fmaxf(mx, __shfl_xor(mx, 2));  mx = fmaxf(mx, __shfl_xor(mx, 1));
    float e0 = (t0 < 100) ? fexp2((v0 - mx) * LOG2E) : 0.f;
    float e1 = (t1 < 100) ? fexp2((v1 - mx) * LOG2E) : 0.f;
    float x0 = (t0 < 100) ? xs[t0] : 0.f;
    float x1 = (t1 < 100) ? xs[t1] : 0.f;
    float se = e0 + e1, sx = e0 * x0 + e1 * x1;
    se += __shfl_xor(se, 32); sx += __shfl_xor(sx, 32);
    se += __shfl_xor(se, 16); sx += __shfl_xor(sx, 16);
    se += __shfl_xor(se, 8);  sx += __shfl_xor(sx, 8);
    se += __shfl_xor(se, 4);  sx += __shfl_xor(sx, 4);
    se += __shfl_xor(se, 2);  sx += __shfl_xor(sx, 2);
    se += __shfl_xor(se, 1);  sx += __shfl_xor(sx, 1);
    if (lane == 0) l_wm = sx * frcp(se * (float)(100 - t));
  }
  __syncthreads();

  // LSTM update for j = tid and tid+256 (gates interleaved: col 4j+g)
  const float wmv = l_wm;
#pragma unroll
  for (int p = 0; p < 2; ++p) {
    int j = tid + (p << 8);
    const f32x4 g4 = (p == 0) ? g4a : g4b;
    float gi = fmaf(wmv, wih_[p][0], bia_[p][0]) + g4[0];
    float gf = fmaf(wmv, wih_[p][1], bia_[p][1]) + g4[1];
    float gg = fmaf(wmv, wih_[p][2], bia_[p][2]) + g4[2];
    float go = fmaf(wmv, wih_[p][3], bia_[p][3]) + g4[3];
    float cn = fsig(gf) * cold[p] + fsig(gi) * ftanh(gg);
    float hn = fsig(go) * ftanh(cn);
    size_t cidx = ((size_t)b << 9) + j;
    cst[cidx] = cn;
    hbf[cidx] = __float2bfloat16(hn);
    if (t >= 84) out[((size_t)b << 13) + ((size_t)(t - 84) << 9) + j] = hn;
  }
}

extern "C" void kernel_launch(void* const* d_in, const int* in_sizes, int n_in,
                              void* d_out, int out_size, void* d_ws, size_t ws_size,
                              hipStream_t stream) {
  const float* x   = (const float*)d_in[0];
  const float* W1w = (const float*)d_in[1];
  const float* W1b = (const float*)d_in[2];
  const float* W2w = (const float*)d_in[3];
  const float* W2b = (const float*)d_in[4];
  const float* vw  = (const float*)d_in[5];
  // d_in[6] = v_b : cancels in softmax, unused
  const float* Wih = (const float*)d_in[7];
  const float* bih = (const float*)d_in[8];
  const float* Whh = (const float*)d_in[9];
  const float* bhh = (const float*)d_in[10];
  float* out = (float*)d_out;

  char* ws = (char*)d_ws;
  __hip_bfloat16* Wall = (__hip_bfloat16*)(ws);           // rows 0..511 = Wcs
  __hip_bfloat16* Wcs = (__hip_bfloat16*)(ws);
  __hip_bfloat16* Wcg = (__hip_bfloat16*)(ws + 524288);   // rows 512..2559
  __hip_bfloat16* hbf = (__hip_bfloat16*)(ws + 2621440);
  float* cst  = (float*)(ws + 4718592);
  float* sbuf = (float*)(ws + 8912896);
  float* gpre = (float*)(ws + 13107200);

  darnn_prologue<<<dim3(512), dim3(256), 0, stream>>>(
      W2w, Whh, Wcs, Wcg, hbf, cst);
  for (int t = 0; t < 100; ++t) {
    darnn_gemm2<<<dim3(512), dim3(256), 0, stream>>>(hbf, Wall, sbuf, gpre);
    darnn_attn_lstm<<<dim3(2048), dim3(256), 0, stream>>>(
        x, W1w, W1b, W2b, vw, sbuf, gpre, Wih, bih, bhh, cst, hbf, out, t);
  }
}

// Round 11
// 2959.954 us; speedup vs baseline: 1.4078x; 1.4078x over previous
//
#include <hip/hip_runtime.h>
#include <hip/hip_bf16.h>

// B=2048, T=100, I=1, H=512. Output: h at t=84..99 -> (2048,16,512) fp32.
// Step: K_A darnn_gemm2 (512 WGs, uniform 64x160 tiles over N=2560:
//         [s | gates] = h @ Wall^T) ;
//       K_B darnn_attn_lstm (2048 WGs, 1 row/WG): logits via 12-node
//         Chebyshev-barycentric interpolation of F_b(x) (I=1 trick),
//         softmax+wmean, fused LSTM.
// ws layout (bytes), total 29884416:
//   Wcs  bf16 [512][512]   @ 0         (= W2_w)          } Wall[2560][512]
//   Wcg  bf16 [2048][512]  @ 524288    (row 4j+g = Whh[g*512+j]) } contiguous
//   hbf  bf16 [2048][512]  @ 2621440
//   cst  f32  [2048][512]  @ 4718592
//   sbuf f32  [2048][512]  @ 8912896
//   gpre f32  [2048][2048] @ 13107200  (col 4j+g, interleaved gates)

typedef __attribute__((ext_vector_type(8))) short s16x8;
typedef __attribute__((ext_vector_type(4))) float f32x4;

#define LOG2E 1.4426950408889634f

__device__ __forceinline__ float fexp2(float x) {
  float r; asm("v_exp_f32 %0, %1\n\ts_nop 1" : "=v"(r) : "v"(x)); return r;
}
__device__ __forceinline__ float frcp(float x) {
  float r; asm("v_rcp_f32 %0, %1\n\ts_nop 1" : "=v"(r) : "v"(x)); return r;
}
__device__ __forceinline__ float ftanh(float y) {   // tanh(y) = 1 - 2/(1+e^{2y})
  return 1.0f - 2.0f * frcp(1.0f + fexp2(y * (2.0f * LOG2E)));
}
__device__ __forceinline__ float fsig(float y) {
  return frcp(1.0f + fexp2(-y * LOG2E));
}

__device__ __forceinline__ void gl_lds16(const void* g, void* l) {
  __builtin_amdgcn_global_load_lds(
      (const __attribute__((address_space(1))) void*)g,
      (__attribute__((address_space(3))) void*)l, 16, 0, 0);
}

// 12 Chebyshev-Lobatto nodes on [-7,7]: xi_k = 7*cos(k*pi/11)
#define N0   7.0f
#define N1   6.71645081f
#define N2   5.88877473f
#define N3   4.58402514f
#define N4   2.90790508f
#define N5   0.99620385f
#define N6  -0.99620385f
#define N7  -2.90790508f
#define N8  -4.58402514f
#define N9  -5.88877473f
#define N10 -6.71645081f
#define N11 -7.0f

// ---------------- prologue: zero h,c ; build bf16 weights ------------------
__global__ __launch_bounds__(256) void darnn_prologue(
    const float* __restrict__ W2w, const float* __restrict__ Whh,
    __hip_bfloat16* __restrict__ Wcs, __hip_bfloat16* __restrict__ Wcg,
    __hip_bfloat16* __restrict__ hbf, float* __restrict__ cst)
{
  const int gtid = blockIdx.x * 256 + threadIdx.x;        // 0..131071
  s16x8 z8 = {0, 0, 0, 0, 0, 0, 0, 0};
  ((s16x8*)hbf)[gtid] = z8;                               // 2048*512 bf16
  f32x4 zf = {0.f, 0.f, 0.f, 0.f};
  ((f32x4*)cst)[gtid] = zf;                               // 2048*512 f32
  ((f32x4*)cst)[gtid + 131072] = zf;
  // Wcs = bf16(W2w), same layout (512*512 = 2 per thread)
  Wcs[2 * gtid]     = __float2bfloat16(W2w[2 * gtid]);
  Wcs[2 * gtid + 1] = __float2bfloat16(W2w[2 * gtid + 1]);
  // Wcg: row r=4j+g <- Whh row g*512+j   (2048*512 = 8 per thread, same row)
  {
    int base = gtid * 8;
    int r = base >> 9, kk = base & 511;
    int j = r >> 2, g = r & 3;
    const float* src = Whh + ((size_t)((g << 9) + j) << 9) + kk;
#pragma unroll
    for (int e = 0; e < 8; ++e) Wcg[base + e] = __float2bfloat16(src[e]);
  }
}

// -------- K_A: uniform combined GEMM [s | gates] = h @ Wall^T --------------
// 512 WGs x 256 thr, tile 64x160, BK=64, XCD-swizzled grid. (byte-identical
// to round-10 measured kernel)
__global__ __launch_bounds__(256, 3) void darnn_gemm2(
    const __hip_bfloat16* __restrict__ hbf, const __hip_bfloat16* __restrict__ Wall,
    float* __restrict__ sbuf, float* __restrict__ gpre)
{
  const int tid = threadIdx.x;
  const int lane = tid & 63, wv = tid >> 6;

  const int wg0 = blockIdx.x;
  const int xcd = wg0 & 7, idx = wg0 >> 3;         // idx 0..63
  const int nt = (xcd << 1) + (idx & 1);           // 0..15
  const int mt = idx >> 1;                         // 0..31

  __shared__ __align__(16) short ldsA[64 * 64];    // 8 KB  (h tile)
  __shared__ __align__(16) short ldsB[160 * 64];   // 20 KB (Wall tile)

  const int m0 = mt << 6, n0 = nt * 160;
  const int wm = wv >> 1, wn = wv & 1;             // wave = 32x80 sub-tile
  const int lr = lane & 15, lq = lane >> 4;
  const int r8 = lane >> 3, kk8 = (lane & 7) << 3;

  f32x4 acc[2][5];
#pragma unroll
  for (int i = 0; i < 2; ++i)
#pragma unroll
    for (int j = 0; j < 5; ++j) acc[i][j] = {0.f, 0.f, 0.f, 0.f};

  for (int k0 = 0; k0 < 512; k0 += 64) {
#pragma unroll
    for (int cc = 0; cc < 7; ++cc) {
      int c = wv * 7 + cc;
      if (c < 8) {
        gl_lds16(hbf + ((size_t)(m0 + (c << 3) + r8) << 9) + (k0 + kk8),
                 (void*)(ldsA + (c << 9)));
      } else {
        int cb = c - 8;
        gl_lds16(Wall + ((size_t)(n0 + (cb << 3) + r8) << 9) + (k0 + kk8),
                 (void*)(ldsB + (cb << 9)));
      }
    }
    __syncthreads();
#pragma unroll
    for (int kh = 0; kh < 2; ++kh) {
      s16x8 af[2], bfr[5];
      int kk = (kh << 5) + (lq << 3);
#pragma unroll
      for (int i = 0; i < 2; ++i)
        af[i] = *(const s16x8*)(ldsA + ((wm << 5) + (i << 4) + lr) * 64 + kk);
#pragma unroll
      for (int j = 0; j < 5; ++j)
        bfr[j] = *(const s16x8*)(ldsB + (wn * 80 + (j << 4) + lr) * 64 + kk);
#pragma unroll
      for (int i = 0; i < 2; ++i)
#pragma unroll
        for (int j = 0; j < 5; ++j)
          acc[i][j] = __builtin_amdgcn_mfma_f32_16x16x32_bf16(
              af[i], bfr[j], acc[i][j], 0, 0, 0);
    }
    __syncthreads();
  }
#pragma unroll
  for (int i = 0; i < 2; ++i)
#pragma unroll
    for (int j = 0; j < 5; ++j) {
      int row0 = m0 + (wm << 5) + (i << 4) + (lq << 2);
      int col = n0 + wn * 80 + (j << 4) + lr;
#pragma unroll
      for (int e = 0; e < 4; ++e) {
        float v = acc[i][j][e];
        if (col < 512) sbuf[((size_t)(row0 + e) << 9) + col] = v;
        else gpre[((size_t)(row0 + e) << 11) + (col - 512)] = v;
      }
    }
}

// ------- K_B: attention (Chebyshev) + LSTM, one batch-row per WG -----------
__global__ __launch_bounds__(256, 4) void darnn_attn_lstm(
    const float* __restrict__ x, const float* __restrict__ W1w,
    const float* __restrict__ W1b, const float* __restrict__ W2b,
    const float* __restrict__ vw, const float* __restrict__ sbuf,
    const float* __restrict__ gpre, const float* __restrict__ Wih,
    const float* __restrict__ bih, const float* __restrict__ bhh,
    float* __restrict__ cst, __hip_bfloat16* __restrict__ hbf,
    float* __restrict__ out, int t)
{
  const int b = blockIdx.x, tid = threadIdx.x;
  const int lane = tid & 63, wv = tid >> 6;

  __shared__ float l_logit[100];
  __shared__ float xs[104];
  __shared__ float Fn[12];
  __shared__ float l_wm;

  // ---- early loads for the LSTM epilogue (j = tid and tid+256) ----
  const f32x4 g4a = *(const f32x4*)(gpre + ((size_t)b << 11) + (tid << 2));
  const f32x4 g4b = *(const f32x4*)(gpre + ((size_t)b << 11) + (tid << 2) + 1024);
  float wih_[2][4], bia_[2][4], cold[2];
#pragma unroll
  for (int p = 0; p < 2; ++p) {
    int j = tid + (p << 8);
#pragma unroll
    for (int g = 0; g < 4; ++g) {
      wih_[p][g] = Wih[(g << 9) + j];
      bia_[p][g] = bih[(g << 9) + j] + bhh[(g << 9) + j];
    }
    cold[p] = cst[((size_t)b << 9) + j];
  }

  if (tid < 100) xs[tid] = x[b * 100 + tid];

  // per-lane slice of 8 h-indices
  float cw1[8], base[8], vvv[8];
  {
    int h0 = lane * 8;
    const f32x4 s0 = *(const f32x4*)(sbuf + ((size_t)b << 9) + h0);
    const f32x4 s1 = *(const f32x4*)(sbuf + ((size_t)b << 9) + h0 + 4);
#pragma unroll
    for (int e = 0; e < 8; ++e) {
      cw1[e] = W1w[h0 + e];
      vvv[e] = vw[h0 + e];
      float s = (e < 4) ? s0[e] : s1[e - 4];
      base[e] = s + W1b[h0 + e] + W2b[h0 + e];
    }
  }

  // ---- node phase: wave wv evaluates F_b at nodes 3wv .. 3wv+2 ----
  {
    float xi0, xi1, xi2;
    switch (wv) {
      case 0:  xi0 = N0; xi1 = N1;  xi2 = N2;  break;
      case 1:  xi0 = N3; xi1 = N4;  xi2 = N5;  break;
      case 2:  xi0 = N6; xi1 = N7;  xi2 = N8;  break;
      default: xi0 = N9; xi1 = N10; xi2 = N11; break;
    }
    float s0 = 0.f, s1 = 0.f, s2 = 0.f;
#pragma unroll
    for (int e = 0; e < 8; ++e) {
      s0 = fmaf(vvv[e], ftanh(fmaf(xi0, cw1[e], base[e])), s0);
      s1 = fmaf(vvv[e], ftanh(fmaf(xi1, cw1[e], base[e])), s1);
      s2 = fmaf(vvv[e], ftanh(fmaf(xi2, cw1[e], base[e])), s2);
    }
    s0 += __shfl_xor(s0, 32); s1 += __shfl_xor(s1, 32); s2 += __shfl_xor(s2, 32);
    s0 += __shfl_xor(s0, 16); s1 += __shfl_xor(s1, 16); s2 += __shfl_xor(s2, 16);
    s0 += __shfl_xor(s0, 8);  s1 += __shfl_xor(s1, 8);  s2 += __shfl_xor(s2, 8);
    s0 += __shfl_xor(s0, 4);  s1 += __shfl_xor(s1, 4);  s2 += __shfl_xor(s2, 4);
    s0 += __shfl_xor(s0, 2);  s1 += __shfl_xor(s1, 2);  s2 += __shfl_xor(s2, 2);
    s0 += __shfl_xor(s0, 1);  s1 += __shfl_xor(s1, 1);  s2 += __shfl_xor(s2, 1);
    if (lane == 0) {
      Fn[3 * wv]     = s0;
      Fn[3 * wv + 1] = s1;
      Fn[3 * wv + 2] = s2;
    }
  }
  __syncthreads();

  // ---- tp phase: one thread per tp, 12-term barycentric interpolation ----
  {
    int tp = t + tid;
    if (tp < 100) {
      float xi = xs[tp];
      float num = 0.f, den = 0.f;
      const float NODES[12] = {N0,N1,N2,N3,N4,N5,N6,N7,N8,N9,N10,N11};
      const float WGTS[12]  = {0.5f,-1.f,1.f,-1.f,1.f,-1.f,1.f,-1.f,1.f,-1.f,1.f,-0.5f};
#pragma unroll
      for (int k = 0; k < 12; ++k) {
        float d = xi - NODES[k];
        d = (d == 0.f) ? 1e-20f : d;
        float r = frcp(d) * WGTS[k];
        num = fmaf(r, Fn[k], num);
        den += r;
      }
      l_logit[tp] = num * frcp(den);
    }
  }
  __syncthreads();

  // softmax over [t,100) + weighted mean of x (wave 0)
  if (wv == 0) {
    int t0 = t + lane, t1 = t + 64 + lane;
    float v0 = (t0 < 100) ? l_logit[t0] : -1e30f;
    float v1 = (t1 < 100) ? l_logit[t1] : -1e30f;
    float mx = fmaxf(v0, v1);
    mx = fmaxf(mx, __shfl_xor(mx, 32)); mx = fmaxf(mx, __shfl_xor(mx, 16));
    mx = fmaxf(mx, __shfl_xor(mx, 8));  mx = fmaxf(mx, __shfl_xor(mx, 4));
    mx = fmaxf(mx, __shfl_xor(mx, 2));  mx = fmaxf(mx, __shfl_xor(mx, 1));
    float e0 = (t0 < 100) ? fexp2((v0 - mx) * LOG2E) : 0.f;
    float e1 = (t1 < 100) ? fexp2((v1 - mx) * LOG2E) : 0.f;
    float x0 = (t0 < 100) ? xs[t0] : 0.f;
    float x1 = (t1 < 100) ? xs[t1] : 0.f;
    float se = e0 + e1, sx = e0 * x0 + e1 * x1;
    se += __shfl_xor(se, 32); sx += __shfl_xor(sx, 32);
    se += __shfl_xor(se, 16); sx += __shfl_xor(sx, 16);
    se += __shfl_xor(se, 8);  sx += __shfl_xor(sx, 8);
    se += __shfl_xor(se, 4);  sx += __shfl_xor(sx, 4);
    se += __shfl_xor(se, 2);  sx += __shfl_xor(sx, 2);
    se += __shfl_xor(se, 1);  sx += __shfl_xor(sx, 1);
    if (lane == 0) l_wm = sx * frcp(se * (float)(100 - t));
  }
  __syncthreads();

  // LSTM update for j = tid and tid+256 (gates interleaved: col 4j+g)
  const float wmv = l_wm;
#pragma unroll
  for (int p = 0; p < 2; ++p) {
    int j = tid + (p << 8);
    const f32x4 g4 = (p == 0) ? g4a : g4b;
    float gi = fmaf(wmv, wih_[p][0], bia_[p][0]) + g4[0];
    float gf = fmaf(wmv, wih_[p][1], bia_[p][1]) + g4[1];
    float gg = fmaf(wmv, wih_[p][2], bia_[p][2]) + g4[2];
    float go = fmaf(wmv, wih_[p][3], bia_[p][3]) + g4[3];
    float cn = fsig(gf) * cold[p] + fsig(gi) * ftanh(gg);
    float hn = fsig(go) * ftanh(cn);
    size_t cidx = ((size_t)b << 9) + j;
    cst[cidx] = cn;
    hbf[cidx] = __float2bfloat16(hn);
    if (t >= 84) out[((size_t)b << 13) + ((size_t)(t - 84) << 9) + j] = hn;
  }
}

extern "C" void kernel_launch(void* const* d_in, const int* in_sizes, int n_in,
                              void* d_out, int out_size, void* d_ws, size_t ws_size,
                              hipStream_t stream) {
  const float* x   = (const float*)d_in[0];
  const float* W1w = (const float*)d_in[1];
  const float* W1b = (const float*)d_in[2];
  const float* W2w = (const float*)d_in[3];
  const float* W2b = (const float*)d_in[4];
  const float* vw  = (const float*)d_in[5];
  // d_in[6] = v_b : cancels in softmax, unused
  const float* Wih = (const float*)d_in[7];
  const float* bih = (const float*)d_in[8];
  const float* Whh = (const float*)d_in[9];
  const float* bhh = (const float*)d_in[10];
  float* out = (float*)d_out;

  char* ws = (char*)d_ws;
  __hip_bfloat16* Wall = (__hip_bfloat16*)(ws);           // rows 0..511 = Wcs
  __hip_bfloat16* Wcs = (__hip_bfloat16*)(ws);
  __hip_bfloat16* Wcg = (__hip_bfloat16*)(ws + 524288);   // rows 512..2559
  __hip_bfloat16* hbf = (__hip_bfloat16*)(ws + 2621440);
  float* cst  = (float*)(ws + 4718592);
  float* sbuf = (float*)(ws + 8912896);
  float* gpre = (float*)(ws + 13107200);

  darnn_prologue<<<dim3(512), dim3(256), 0, stream>>>(
      W2w, Whh, Wcs, Wcg, hbf, cst);
  for (int t = 0; t < 100; ++t) {
    darnn_gemm2<<<dim3(512), dim3(256), 0, stream>>>(hbf, Wall, sbuf, gpre);
    darnn_attn_lstm<<<dim3(2048), dim3(256), 0, stream>>>(
        x, W1w, W1b, W2b, vw, sbuf, gpre, Wih, bih, bhh, cst, hbf, out, t);
  }
}